// Round 1
// baseline (4652.210 us; speedup 1.0000x reference)
//
#include <hip/hip_runtime.h>

typedef __attribute__((ext_vector_type(8))) short short8;
typedef __attribute__((ext_vector_type(4))) float floatx4;

#define DIM   1024
#define SEQ   1024
#define BATCH 4
#define NHEAD 16
#define HDIM  64
#define MLPD  4096
#define DEPTH 6
#define MTOK  (BATCH*SEQ)   /* 4096 token rows */

__device__ __forceinline__ unsigned short f2bf(float f) {
    union { float f; unsigned u; } v; v.f = f;
    unsigned r = v.u + 0x7fffu + ((v.u >> 16) & 1u);   // RNE
    return (unsigned short)(r >> 16);
}

// ---------------------------------------------------------------------------
// LayerNorm: one block per token row. fp32 in -> bf16 out (w,b applied).
// ---------------------------------------------------------------------------
__global__ __launch_bounds__(256) void ln_kernel(
    const float* __restrict__ x, const float* __restrict__ w,
    const float* __restrict__ b, unsigned short* __restrict__ y)
{
    __shared__ float red[8];
    const int row = blockIdx.x;
    const int t = threadIdx.x;
    const float4 v = ((const float4*)(x + (size_t)row * DIM))[t];
    float s = v.x + v.y + v.z + v.w;
#pragma unroll
    for (int m = 1; m < 64; m <<= 1) s += __shfl_xor(s, m);
    if ((t & 63) == 0) red[t >> 6] = s;
    __syncthreads();
    const float mu = (red[0] + red[1] + red[2] + red[3]) * (1.0f / DIM);
    const float d0 = v.x - mu, d1 = v.y - mu, d2 = v.z - mu, d3 = v.w - mu;
    float q = d0 * d0 + d1 * d1 + d2 * d2 + d3 * d3;
#pragma unroll
    for (int m = 1; m < 64; m <<= 1) q += __shfl_xor(q, m);
    if ((t & 63) == 0) red[4 + (t >> 6)] = q;
    __syncthreads();
    const float var = (red[4] + red[5] + red[6] + red[7]) * (1.0f / DIM);
    const float rs = rsqrtf(var + 1e-5f);
    const float4 wv = ((const float4*)w)[t];
    const float4 bv = ((const float4*)b)[t];
    ushort4 o;
    o.x = f2bf(d0 * rs * wv.x + bv.x);
    o.y = f2bf(d1 * rs * wv.y + bv.y);
    o.z = f2bf(d2 * rs * wv.z + bv.z);
    o.w = f2bf(d3 * rs * wv.w + bv.w);
    ((ushort4*)(y + (size_t)row * DIM))[t] = o;
}

// ---------------------------------------------------------------------------
// GEMM: C[M,N] = A[M,K](bf16) @ B[K,N](fp32->bf16) + bias, 128x128x32 tiles.
// MODE 0: out bf16 = acc+bias
// MODE 1: out bf16 = gelu(acc+bias)   (exact, erf)
// MODE 2: out fp32 += acc+bias        (residual accumulate, in-place)
// 4 waves, each computes 64x64 as 4x4 mfma_f32_16x16x32_bf16 tiles.
// ---------------------------------------------------------------------------
template <int MODE>
__global__ __launch_bounds__(256) void gemm_bf16(
    const unsigned short* __restrict__ A, const float* __restrict__ B,
    const float* __restrict__ bias, void* __restrict__ Cout,
    int M, int K, int N)
{
    __shared__ __align__(16) unsigned short Al[128 * 40];  // [row][k] pad 32->40
    __shared__ __align__(16) unsigned short Bl[128 * 40];  // [col][k] (B transposed)

    const int bm = blockIdx.y * 128, bn = blockIdx.x * 128;
    const int tid = threadIdx.x;
    const int lane = tid & 63, wid = tid >> 6;
    const int lm = lane & 15, quad = lane >> 4;
    const int wm = (wid >> 1) * 64, wn = (wid & 1) * 64;

    floatx4 acc[4][4] = {};

    const int ar0 = tid >> 2, ac = (tid & 3) * 8;     // A: 64 rows/pass x 4 chunks
    const int br0 = tid >> 5, bc = (tid & 31) * 4;    // B: 8 rows/pass x 32 col4s

    for (int kt = 0; kt < K; kt += 32) {
        // stage A tile (bf16, straight copy, 16B per thread per pass)
#pragma unroll
        for (int p = 0; p < 2; p++) {
            const int r = ar0 + p * 64;
            const int4 v = *(const int4*)&A[(size_t)(bm + r) * K + kt + ac];
            *(int4*)&Al[r * 40 + ac] = v;
        }
        // stage B tile transposed, fp32 -> bf16
#pragma unroll
        for (int p = 0; p < 4; p++) {
            const int r = br0 + p * 8;
            const float4 v = *(const float4*)&B[(size_t)(kt + r) * N + bn + bc];
            Bl[(bc + 0) * 40 + r] = f2bf(v.x);
            Bl[(bc + 1) * 40 + r] = f2bf(v.y);
            Bl[(bc + 2) * 40 + r] = f2bf(v.z);
            Bl[(bc + 3) * 40 + r] = f2bf(v.w);
        }
        __syncthreads();
        short8 af[4], bf[4];
#pragma unroll
        for (int i = 0; i < 4; i++)
            af[i] = *(const short8*)&Al[(wm + i * 16 + lm) * 40 + quad * 8];
#pragma unroll
        for (int i = 0; i < 4; i++)
            bf[i] = *(const short8*)&Bl[(wn + i * 16 + lm) * 40 + quad * 8];
#pragma unroll
        for (int i = 0; i < 4; i++)
#pragma unroll
            for (int j = 0; j < 4; j++)
                acc[i][j] = __builtin_amdgcn_mfma_f32_16x16x32_bf16(
                    af[i], bf[j], acc[i][j], 0, 0, 0);
        __syncthreads();
    }

    // epilogue (C/D layout: col = lane&15, row = quad*4 + reg)
#pragma unroll
    for (int i = 0; i < 4; i++) {
        const int row = bm + wm + i * 16 + quad * 4;
#pragma unroll
        for (int j = 0; j < 4; j++) {
            const int col = bn + wn + j * 16 + lm;
            const float bb = bias[col];
#pragma unroll
            for (int r = 0; r < 4; r++) {
                float v = acc[i][j][r] + bb;
                const size_t idx = (size_t)(row + r) * N + col;
                if constexpr (MODE == 0) {
                    ((unsigned short*)Cout)[idx] = f2bf(v);
                } else if constexpr (MODE == 1) {
                    const float g = 0.5f * v * (1.0f + erff(v * 0.70710678118654752f));
                    ((unsigned short*)Cout)[idx] = f2bf(g);
                } else {
                    ((float*)Cout)[idx] += v;
                }
            }
        }
    }
}

// ---------------------------------------------------------------------------
// V transpose: qkv[:, 2048 + h*64 + hd] -> Vt[b,h,hd,n]  (bf16)
// grid (64 bh, 16 ntiles), 64x64 tile via LDS
// ---------------------------------------------------------------------------
__global__ __launch_bounds__(256) void vtrans_kernel(
    const unsigned short* __restrict__ qkv, unsigned short* __restrict__ Vt)
{
    __shared__ unsigned short tile[64][65];
    const int bh = blockIdx.x, nt = blockIdx.y;
    const int b = bh >> 4, h = bh & 15;
    const int t = threadIdx.x;
#pragma unroll
    for (int p = t; p < 4096; p += 256) {
        const int n = p >> 6, c = p & 63;
        tile[n][c] = qkv[(size_t)(b * SEQ + nt * 64 + n) * (3 * DIM) + 2 * DIM + h * HDIM + c];
    }
    __syncthreads();
#pragma unroll
    for (int p = t; p < 4096; p += 256) {
        const int hd = p >> 6, n = p & 63;
        Vt[((size_t)bh * HDIM + hd) * SEQ + nt * 64 + n] = tile[n][hd];
    }
}

// ---------------------------------------------------------------------------
// Fused flash attention. grid (64 bh, 16), 4 waves/block, one 16-row Q tile
// per wave, K-tiles of 32 keys. Q,K read from qkv buffer; V from Vt.
// Out: O[b, n, h, hd] = [4096,1024] bf16.
// ---------------------------------------------------------------------------
__global__ __launch_bounds__(256) void attn_kernel(
    const unsigned short* __restrict__ qkv, const unsigned short* __restrict__ Vt,
    unsigned short* __restrict__ O)
{
    __shared__ __align__(16) unsigned short P[4][16 * 40];
    const int bh = blockIdx.x;
    const int b = bh >> 4, h = bh & 15;
    const int tid = threadIdx.x, lane = tid & 63, wid = tid >> 6;
    const int lm = lane & 15, quad = lane >> 4;
    const int q0 = (blockIdx.y * 4 + wid) * 16;

    const unsigned short* Qbase = qkv + (size_t)(b * SEQ) * (3 * DIM) + h * HDIM;
    const unsigned short* Kbase = Qbase + DIM;
    const unsigned short* Vbase = Vt + (size_t)bh * HDIM * SEQ;

    short8 aq[2];
#pragma unroll
    for (int t = 0; t < 2; t++)
        aq[t] = *(const short8*)&Qbase[(size_t)(q0 + lm) * (3 * DIM) + t * 32 + quad * 8];

    floatx4 o[4] = {};
    float mi[4], li[4];
#pragma unroll
    for (int r = 0; r < 4; r++) { mi[r] = -1e30f; li[r] = 0.0f; }
    unsigned short* Pw = P[wid];
    const float scale = 0.03125f;   // 1024^-0.5

    for (int kt = 0; kt < SEQ; kt += 32) {
        short8 bk[2][2];
#pragma unroll
        for (int s = 0; s < 2; s++)
#pragma unroll
            for (int t = 0; t < 2; t++)
                bk[s][t] = *(const short8*)&Kbase[(size_t)(kt + s * 16 + lm) * (3 * DIM) + t * 32 + quad * 8];
        floatx4 s0 = {}, s1 = {};
        s0 = __builtin_amdgcn_mfma_f32_16x16x32_bf16(aq[0], bk[0][0], s0, 0, 0, 0);
        s0 = __builtin_amdgcn_mfma_f32_16x16x32_bf16(aq[1], bk[0][1], s0, 0, 0, 0);
        s1 = __builtin_amdgcn_mfma_f32_16x16x32_bf16(aq[0], bk[1][0], s1, 0, 0, 0);
        s1 = __builtin_amdgcn_mfma_f32_16x16x32_bf16(aq[1], bk[1][1], s1, 0, 0, 0);

        float p0[4], p1[4];
#pragma unroll
        for (int r = 0; r < 4; r++) {
            const float x0 = s0[r] * scale, x1 = s1[r] * scale;
            float tmx = fmaxf(x0, x1);
#pragma unroll
            for (int m = 1; m < 16; m <<= 1) tmx = fmaxf(tmx, __shfl_xor(tmx, m));
            const float mn = fmaxf(mi[r], tmx);
            const float al = __expf(mi[r] - mn);
            p0[r] = __expf(x0 - mn);
            p1[r] = __expf(x1 - mn);
            float rsum = p0[r] + p1[r];
#pragma unroll
            for (int m = 1; m < 16; m <<= 1) rsum += __shfl_xor(rsum, m);
            li[r] = li[r] * al + rsum;
            mi[r] = mn;
#pragma unroll
            for (int ti = 0; ti < 4; ti++) o[ti][r] *= al;
        }
        // P: C-layout -> A-layout via LDS round trip
#pragma unroll
        for (int r = 0; r < 4; r++) {
            Pw[(quad * 4 + r) * 40 + lm]      = f2bf(p0[r]);
            Pw[(quad * 4 + r) * 40 + 16 + lm] = f2bf(p1[r]);
        }
        __syncthreads();
        const short8 pa = *(const short8*)&Pw[lm * 40 + quad * 8];
#pragma unroll
        for (int ti = 0; ti < 4; ti++) {
            const short8 bv = *(const short8*)&Vbase[(size_t)(ti * 16 + lm) * SEQ + kt + quad * 8];
            o[ti] = __builtin_amdgcn_mfma_f32_16x16x32_bf16(pa, bv, o[ti], 0, 0, 0);
        }
        __syncthreads();
    }
#pragma unroll
    for (int r = 0; r < 4; r++) {
        const float inv = 1.0f / li[r];
        const int qrow = q0 + quad * 4 + r;
        const size_t orow = (size_t)(b * SEQ + qrow) * DIM + h * HDIM;
#pragma unroll
        for (int ti = 0; ti < 4; ti++)
            O[orow + ti * 16 + lm] = f2bf(o[ti][r] * inv);
    }
}

// ---------------------------------------------------------------------------
extern "C" void kernel_launch(void* const* d_in, const int* in_sizes, int n_in,
                              void* d_out, int out_size, void* d_ws, size_t ws_size,
                              hipStream_t stream)
{
    (void)in_sizes; (void)n_in; (void)out_size; (void)ws_size;
    const float* x      = (const float*)d_in[0];
    const float* ln1_w  = (const float*)d_in[1];
    const float* ln1_b  = (const float*)d_in[2];
    const float* qkv_w  = (const float*)d_in[3];
    const float* qkv_b  = (const float*)d_in[4];
    const float* proj_w = (const float*)d_in[5];
    const float* proj_b = (const float*)d_in[6];
    const float* ln2_w  = (const float*)d_in[7];
    const float* ln2_b  = (const float*)d_in[8];
    const float* mlp_w1 = (const float*)d_in[9];
    const float* mlp_b1 = (const float*)d_in[10];
    const float* mlp_w2 = (const float*)d_in[11];
    const float* mlp_b2 = (const float*)d_in[12];

    char* p = (char*)d_ws;
    float* xbuf = (float*)p;                    p += (size_t)MTOK * DIM * 4;   // 16 MB
    unsigned short* y = (unsigned short*)p;     p += (size_t)MTOK * DIM * 2;   //  8 MB
    unsigned short* big = (unsigned short*)p;   p += (size_t)MTOK * MLPD * 2;  // 32 MB (qkv 24MB / H 32MB)
    unsigned short* Vt = (unsigned short*)p;    p += (size_t)MTOK * DIM * 2;   //  8 MB
    unsigned short* attno = (unsigned short*)p; p += (size_t)MTOK * DIM * 2;   //  8 MB

    hipMemcpyAsync(xbuf, x, (size_t)MTOK * DIM * 4, hipMemcpyDeviceToDevice, stream);

    for (int l = 0; l < DEPTH; l++) {
        ln_kernel<<<MTOK, 256, 0, stream>>>(xbuf, ln1_w + l * DIM, ln1_b + l * DIM, y);
        gemm_bf16<0><<<dim3(3 * DIM / 128, MTOK / 128), 256, 0, stream>>>(
            y, qkv_w + (size_t)l * DIM * 3 * DIM, qkv_b + (size_t)l * 3 * DIM,
            big, MTOK, DIM, 3 * DIM);
        vtrans_kernel<<<dim3(64, 16), 256, 0, stream>>>(big, Vt);
        attn_kernel<<<dim3(64, 16), 256, 0, stream>>>(big, Vt, attno);
        gemm_bf16<2><<<dim3(DIM / 128, MTOK / 128), 256, 0, stream>>>(
            attno, proj_w + (size_t)l * DIM * DIM, proj_b + (size_t)l * DIM,
            xbuf, MTOK, DIM, DIM);
        ln_kernel<<<MTOK, 256, 0, stream>>>(xbuf, ln2_w + l * DIM, ln2_b + l * DIM, y);
        gemm_bf16<1><<<dim3(MLPD / 128, MTOK / 128), 256, 0, stream>>>(
            y, mlp_w1 + (size_t)l * DIM * MLPD, mlp_b1 + (size_t)l * MLPD,
            big, MTOK, DIM, MLPD);
        gemm_bf16<2><<<dim3(DIM / 128, MTOK / 128), 256, 0, stream>>>(
            big, mlp_w2 + (size_t)l * MLPD * DIM, mlp_b2 + (size_t)l * DIM,
            xbuf, MTOK, MLPD, DIM);
    }
    hipMemcpyAsync(d_out, xbuf, (size_t)MTOK * DIM * 4, hipMemcpyDeviceToDevice, stream);
}

// Round 2
// 2646.882 us; speedup vs baseline: 1.7576x; 1.7576x over previous
//
#include <hip/hip_runtime.h>

typedef __attribute__((ext_vector_type(8))) short short8;
typedef __attribute__((ext_vector_type(4))) float floatx4;

#define DIM   1024
#define SEQ   1024
#define BATCH 4
#define NHEAD 16
#define HDIM  64
#define MLPD  4096
#define DEPTH 6
#define MTOK  (BATCH*SEQ)   /* 4096 token rows */

__device__ __forceinline__ unsigned short f2bf(float f) {
    union { float f; unsigned u; } v; v.f = f;
    unsigned r = v.u + 0x7fffu + ((v.u >> 16) & 1u);   // RNE
    return (unsigned short)(r >> 16);
}

__device__ __forceinline__ void gld16(const void* g, void* l) {
    __builtin_amdgcn_global_load_lds(
        (const __attribute__((address_space(1))) unsigned int*)g,
        (__attribute__((address_space(3))) unsigned int*)l, 16, 0, 0);
}

// ---------------------------------------------------------------------------
// LayerNorm: one block per token row. fp32 in -> bf16 out (w,b applied).
// ---------------------------------------------------------------------------
__global__ __launch_bounds__(256) void ln_kernel(
    const float* __restrict__ x, const float* __restrict__ w,
    const float* __restrict__ b, unsigned short* __restrict__ y)
{
    __shared__ float red[8];
    const int row = blockIdx.x;
    const int t = threadIdx.x;
    const float4 v = ((const float4*)(x + (size_t)row * DIM))[t];
    float s = v.x + v.y + v.z + v.w;
#pragma unroll
    for (int m = 1; m < 64; m <<= 1) s += __shfl_xor(s, m);
    if ((t & 63) == 0) red[t >> 6] = s;
    __syncthreads();
    const float mu = (red[0] + red[1] + red[2] + red[3]) * (1.0f / DIM);
    const float d0 = v.x - mu, d1 = v.y - mu, d2 = v.z - mu, d3 = v.w - mu;
    float q = d0 * d0 + d1 * d1 + d2 * d2 + d3 * d3;
#pragma unroll
    for (int m = 1; m < 64; m <<= 1) q += __shfl_xor(q, m);
    if ((t & 63) == 0) red[4 + (t >> 6)] = q;
    __syncthreads();
    const float var = (red[4] + red[5] + red[6] + red[7]) * (1.0f / DIM);
    const float rs = rsqrtf(var + 1e-5f);
    const float4 wv = ((const float4*)w)[t];
    const float4 bv = ((const float4*)b)[t];
    ushort4 o;
    o.x = f2bf(d0 * rs * wv.x + bv.x);
    o.y = f2bf(d1 * rs * wv.y + bv.y);
    o.z = f2bf(d2 * rs * wv.z + bv.z);
    o.w = f2bf(d3 * rs * wv.w + bv.w);
    ((ushort4*)(y + (size_t)row * DIM))[t] = o;
}

// ---------------------------------------------------------------------------
// Weight prepass: W [K][N] fp32 -> Wt [N][K] bf16 (64x64 tiles via LDS).
// ---------------------------------------------------------------------------
__global__ __launch_bounds__(256) void wtrans_kernel(
    const float* __restrict__ W, unsigned short* __restrict__ Wt, int K, int N)
{
    __shared__ float tile[64][65];
    const int n0 = blockIdx.x * 64, k0 = blockIdx.y * 64;
    const int t = threadIdx.x;
#pragma unroll
    for (int p = t; p < 1024; p += 256) {
        const int k = p >> 4, nq = (p & 15) * 4;
        const float4 v = *(const float4*)&W[(size_t)(k0 + k) * N + n0 + nq];
        tile[k][nq + 0] = v.x; tile[k][nq + 1] = v.y;
        tile[k][nq + 2] = v.z; tile[k][nq + 3] = v.w;
    }
    __syncthreads();
#pragma unroll
    for (int p = t; p < 1024; p += 256) {
        const int n = p >> 4, kq = (p & 15) * 4;
        ushort4 o;
        o.x = f2bf(tile[kq + 0][n]); o.y = f2bf(tile[kq + 1][n]);
        o.z = f2bf(tile[kq + 2][n]); o.w = f2bf(tile[kq + 3][n]);
        *(ushort4*)&Wt[(size_t)(n0 + n) * K + k0 + kq] = o;
    }
}

// ---------------------------------------------------------------------------
// m97-style GEMM: C[M,N] = A[M,K](bf16) @ Bt[N,K](bf16)^T + bias.
// 128x128x32 tiles, global_load_lds width-16 staging, unpadded LDS.
// MODE 0: out bf16 = acc+bias
// MODE 1: out bf16 = gelu(acc+bias)   (exact, erf)
// MODE 2: out fp32 += acc+bias        (residual accumulate, in-place)
// ---------------------------------------------------------------------------
template <int MODE>
__global__ __launch_bounds__(256) void gemm_m97(
    const unsigned short* __restrict__ A, const unsigned short* __restrict__ Bt,
    const float* __restrict__ bias, void* __restrict__ Cout,
    int M, int K, int N)
{
    __shared__ __align__(16) unsigned short Al[128 * 32];
    __shared__ __align__(16) unsigned short Bl[128 * 32];

    const int bm = blockIdx.y * 128, bn = blockIdx.x * 128;
    const int tid = threadIdx.x;
    const int lane = tid & 63, wid = tid >> 6;
    const int lm = lane & 15, quad = lane >> 4;
    const int wm = (wid >> 1) * 64, wn = (wid & 1) * 64;

    floatx4 acc[4][4] = {};

    // staging: wave w owns rows [w*32, w*32+32) of each tile, 2 instrs of 16 rows.
    // LDS dest is wave-uniform base + lane*16B == [row][k] contiguous layout.
    const unsigned short* gA = A + (size_t)(bm + wid * 32 + (lane >> 2)) * K + (lane & 3) * 8;
    const unsigned short* gB = Bt + (size_t)(bn + wid * 32 + (lane >> 2)) * K + (lane & 3) * 8;
    unsigned short* lA = &Al[wid * 32 * 32];
    unsigned short* lB = &Bl[wid * 32 * 32];

    for (int kt = 0; kt < K; kt += 32) {
        gld16(gA + kt, lA);
        gld16(gA + (size_t)16 * K + kt, lA + 16 * 32);
        gld16(gB + kt, lB);
        gld16(gB + (size_t)16 * K + kt, lB + 16 * 32);
        __syncthreads();
        short8 af[4], bf[4];
#pragma unroll
        for (int i = 0; i < 4; i++)
            af[i] = *(const short8*)&Al[(wm + i * 16 + lm) * 32 + quad * 8];
#pragma unroll
        for (int i = 0; i < 4; i++)
            bf[i] = *(const short8*)&Bl[(wn + i * 16 + lm) * 32 + quad * 8];
#pragma unroll
        for (int i = 0; i < 4; i++)
#pragma unroll
            for (int j = 0; j < 4; j++)
                acc[i][j] = __builtin_amdgcn_mfma_f32_16x16x32_bf16(
                    af[i], bf[j], acc[i][j], 0, 0, 0);
        __syncthreads();
    }

    // epilogue (C/D layout: col = lane&15, row = quad*4 + reg)
#pragma unroll
    for (int i = 0; i < 4; i++) {
        const int row = bm + wm + i * 16 + quad * 4;
#pragma unroll
        for (int j = 0; j < 4; j++) {
            const int col = bn + wn + j * 16 + lm;
            const float bb = bias[col];
#pragma unroll
            for (int r = 0; r < 4; r++) {
                float v = acc[i][j][r] + bb;
                const size_t idx = (size_t)(row + r) * N + col;
                if constexpr (MODE == 0) {
                    ((unsigned short*)Cout)[idx] = f2bf(v);
                } else if constexpr (MODE == 1) {
                    const float g = 0.5f * v * (1.0f + erff(v * 0.70710678118654752f));
                    ((unsigned short*)Cout)[idx] = f2bf(g);
                } else {
                    ((float*)Cout)[idx] += v;
                }
            }
        }
    }
}

// ---------------------------------------------------------------------------
// V transpose: qkv[:, 2048 + h*64 + hd] -> Vt[b,h,hd,n]  (bf16)
// ---------------------------------------------------------------------------
__global__ __launch_bounds__(256) void vtrans_kernel(
    const unsigned short* __restrict__ qkv, unsigned short* __restrict__ Vt)
{
    __shared__ unsigned short tile[64][65];
    const int bh = blockIdx.x, nt = blockIdx.y;
    const int b = bh >> 4, h = bh & 15;
    const int t = threadIdx.x;
#pragma unroll
    for (int p = t; p < 4096; p += 256) {
        const int n = p >> 6, c = p & 63;
        tile[n][c] = qkv[(size_t)(b * SEQ + nt * 64 + n) * (3 * DIM) + 2 * DIM + h * HDIM + c];
    }
    __syncthreads();
#pragma unroll
    for (int p = t; p < 4096; p += 256) {
        const int hd = p >> 6, n = p & 63;
        Vt[((size_t)bh * HDIM + hd) * SEQ + nt * 64 + n] = tile[n][hd];
    }
}

// ---------------------------------------------------------------------------
// Fused flash attention. grid (64 bh, 16), 4 waves/block, one 16-row Q tile
// per wave, K-tiles of 32 keys. Out: O[b, n, h, hd] bf16.
// ---------------------------------------------------------------------------
__global__ __launch_bounds__(256) void attn_kernel(
    const unsigned short* __restrict__ qkv, const unsigned short* __restrict__ Vt,
    unsigned short* __restrict__ O)
{
    __shared__ __align__(16) unsigned short P[4][16 * 40];
    const int bh = blockIdx.x;
    const int b = bh >> 4, h = bh & 15;
    const int tid = threadIdx.x, lane = tid & 63, wid = tid >> 6;
    const int lm = lane & 15, quad = lane >> 4;
    const int q0 = (blockIdx.y * 4 + wid) * 16;

    const unsigned short* Qbase = qkv + (size_t)(b * SEQ) * (3 * DIM) + h * HDIM;
    const unsigned short* Kbase = Qbase + DIM;
    const unsigned short* Vbase = Vt + (size_t)bh * HDIM * SEQ;

    short8 aq[2];
#pragma unroll
    for (int t = 0; t < 2; t++)
        aq[t] = *(const short8*)&Qbase[(size_t)(q0 + lm) * (3 * DIM) + t * 32 + quad * 8];

    floatx4 o[4] = {};
    float mi[4], li[4];
#pragma unroll
    for (int r = 0; r < 4; r++) { mi[r] = -1e30f; li[r] = 0.0f; }
    unsigned short* Pw = P[wid];
    const float scale = 0.03125f;   // 1024^-0.5

    for (int kt = 0; kt < SEQ; kt += 32) {
        short8 bk[2][2];
#pragma unroll
        for (int s = 0; s < 2; s++)
#pragma unroll
            for (int t = 0; t < 2; t++)
                bk[s][t] = *(const short8*)&Kbase[(size_t)(kt + s * 16 + lm) * (3 * DIM) + t * 32 + quad * 8];
        floatx4 s0 = {}, s1 = {};
        s0 = __builtin_amdgcn_mfma_f32_16x16x32_bf16(aq[0], bk[0][0], s0, 0, 0, 0);
        s0 = __builtin_amdgcn_mfma_f32_16x16x32_bf16(aq[1], bk[0][1], s0, 0, 0, 0);
        s1 = __builtin_amdgcn_mfma_f32_16x16x32_bf16(aq[0], bk[1][0], s1, 0, 0, 0);
        s1 = __builtin_amdgcn_mfma_f32_16x16x32_bf16(aq[1], bk[1][1], s1, 0, 0, 0);

        float p0[4], p1[4];
#pragma unroll
        for (int r = 0; r < 4; r++) {
            const float x0 = s0[r] * scale, x1 = s1[r] * scale;
            float tmx = fmaxf(x0, x1);
#pragma unroll
            for (int m = 1; m < 16; m <<= 1) tmx = fmaxf(tmx, __shfl_xor(tmx, m));
            const float mn = fmaxf(mi[r], tmx);
            const float al = __expf(mi[r] - mn);
            p0[r] = __expf(x0 - mn);
            p1[r] = __expf(x1 - mn);
            float rsum = p0[r] + p1[r];
#pragma unroll
            for (int m = 1; m < 16; m <<= 1) rsum += __shfl_xor(rsum, m);
            li[r] = li[r] * al + rsum;
            mi[r] = mn;
#pragma unroll
            for (int ti = 0; ti < 4; ti++) o[ti][r] *= al;
        }
        // P: C-layout -> A-layout via LDS round trip
#pragma unroll
        for (int r = 0; r < 4; r++) {
            Pw[(quad * 4 + r) * 40 + lm]      = f2bf(p0[r]);
            Pw[(quad * 4 + r) * 40 + 16 + lm] = f2bf(p1[r]);
        }
        __syncthreads();
        const short8 pa = *(const short8*)&Pw[lm * 40 + quad * 8];
#pragma unroll
        for (int ti = 0; ti < 4; ti++) {
            const short8 bv = *(const short8*)&Vbase[(size_t)(ti * 16 + lm) * SEQ + kt + quad * 8];
            o[ti] = __builtin_amdgcn_mfma_f32_16x16x32_bf16(pa, bv, o[ti], 0, 0, 0);
        }
        __syncthreads();
    }
#pragma unroll
    for (int r = 0; r < 4; r++) {
        const float inv = 1.0f / li[r];
        const int qrow = q0 + quad * 4 + r;
        const size_t orow = (size_t)(b * SEQ + qrow) * DIM + h * HDIM;
#pragma unroll
        for (int ti = 0; ti < 4; ti++)
            O[orow + ti * 16 + lm] = f2bf(o[ti][r] * inv);
    }
}

// ---------------------------------------------------------------------------
extern "C" void kernel_launch(void* const* d_in, const int* in_sizes, int n_in,
                              void* d_out, int out_size, void* d_ws, size_t ws_size,
                              hipStream_t stream)
{
    (void)in_sizes; (void)n_in; (void)out_size; (void)ws_size;
    const float* x      = (const float*)d_in[0];
    const float* ln1_w  = (const float*)d_in[1];
    const float* ln1_b  = (const float*)d_in[2];
    const float* qkv_w  = (const float*)d_in[3];
    const float* qkv_b  = (const float*)d_in[4];
    const float* proj_w = (const float*)d_in[5];
    const float* proj_b = (const float*)d_in[6];
    const float* ln2_w  = (const float*)d_in[7];
    const float* ln2_b  = (const float*)d_in[8];
    const float* mlp_w1 = (const float*)d_in[9];
    const float* mlp_b1 = (const float*)d_in[10];
    const float* mlp_w2 = (const float*)d_in[11];
    const float* mlp_b2 = (const float*)d_in[12];

    char* p = (char*)d_ws;
    float* xbuf = (float*)p;                    p += (size_t)MTOK * DIM * 4;   // 16 MB
    unsigned short* y = (unsigned short*)p;     p += (size_t)MTOK * DIM * 2;   //  8 MB
    unsigned short* big = (unsigned short*)p;   p += (size_t)MTOK * MLPD * 2;  // 32 MB (qkv 24MB / H 32MB)
    unsigned short* Vt = (unsigned short*)p;    p += (size_t)MTOK * DIM * 2;   //  8 MB
    unsigned short* attno = (unsigned short*)p; p += (size_t)MTOK * DIM * 2;   //  8 MB
    // per-layer bf16 transposed weights (reused across layers)
    unsigned short* qkvT = (unsigned short*)p;  p += (size_t)DIM * 3 * DIM * 2;   // 6 MB
    unsigned short* projT = (unsigned short*)p; p += (size_t)DIM * DIM * 2;       // 2 MB
    unsigned short* mlp1T = (unsigned short*)p; p += (size_t)DIM * MLPD * 2;      // 8 MB
    unsigned short* mlp2T = (unsigned short*)p; p += (size_t)MLPD * DIM * 2;      // 8 MB

    hipMemcpyAsync(xbuf, x, (size_t)MTOK * DIM * 4, hipMemcpyDeviceToDevice, stream);

    for (int l = 0; l < DEPTH; l++) {
        // weight prepass: fp32 [K][N] -> bf16 [N][K], leaves weights L2/L3-hot
        wtrans_kernel<<<dim3(3 * DIM / 64, DIM / 64), 256, 0, stream>>>(
            qkv_w + (size_t)l * DIM * 3 * DIM, qkvT, DIM, 3 * DIM);
        wtrans_kernel<<<dim3(DIM / 64, DIM / 64), 256, 0, stream>>>(
            proj_w + (size_t)l * DIM * DIM, projT, DIM, DIM);
        wtrans_kernel<<<dim3(MLPD / 64, DIM / 64), 256, 0, stream>>>(
            mlp_w1 + (size_t)l * DIM * MLPD, mlp1T, DIM, MLPD);
        wtrans_kernel<<<dim3(DIM / 64, MLPD / 64), 256, 0, stream>>>(
            mlp_w2 + (size_t)l * MLPD * DIM, mlp2T, MLPD, DIM);

        ln_kernel<<<MTOK, 256, 0, stream>>>(xbuf, ln1_w + l * DIM, ln1_b + l * DIM, y);
        gemm_m97<0><<<dim3(3 * DIM / 128, MTOK / 128), 256, 0, stream>>>(
            y, qkvT, qkv_b + (size_t)l * 3 * DIM, big, MTOK, DIM, 3 * DIM);
        vtrans_kernel<<<dim3(64, 16), 256, 0, stream>>>(big, Vt);
        attn_kernel<<<dim3(64, 16), 256, 0, stream>>>(big, Vt, attno);
        gemm_m97<2><<<dim3(DIM / 128, MTOK / 128), 256, 0, stream>>>(
            attno, projT, proj_b + (size_t)l * DIM, xbuf, MTOK, DIM, DIM);
        ln_kernel<<<MTOK, 256, 0, stream>>>(xbuf, ln2_w + l * DIM, ln2_b + l * DIM, y);
        gemm_m97<1><<<dim3(MLPD / 128, MTOK / 128), 256, 0, stream>>>(
            y, mlp1T, mlp_b1 + (size_t)l * MLPD, big, MTOK, DIM, MLPD);
        gemm_m97<2><<<dim3(DIM / 128, MTOK / 128), 256, 0, stream>>>(
            big, mlp2T, mlp_b2 + (size_t)l * DIM, xbuf, MTOK, MLPD, DIM);
    }
    hipMemcpyAsync(d_out, xbuf, (size_t)MTOK * DIM * 4, hipMemcpyDeviceToDevice, stream);
}

// Round 3
// 2514.328 us; speedup vs baseline: 1.8503x; 1.0527x over previous
//
#include <hip/hip_runtime.h>

typedef __attribute__((ext_vector_type(8))) short short8;
typedef __attribute__((ext_vector_type(4))) float floatx4;

#define DIM   1024
#define SEQ   1024
#define BATCH 4
#define NHEAD 16
#define HDIM  64
#define MLPD  4096
#define DEPTH 6
#define MTOK  (BATCH*SEQ)   /* 4096 token rows */

__device__ __forceinline__ unsigned short f2bf(float f) {
    union { float f; unsigned u; } v; v.f = f;
    unsigned r = v.u + 0x7fffu + ((v.u >> 16) & 1u);   // RNE
    return (unsigned short)(r >> 16);
}

__device__ __forceinline__ void gld16(const void* g, void* l) {
    __builtin_amdgcn_global_load_lds(
        (const __attribute__((address_space(1))) unsigned int*)g,
        (__attribute__((address_space(3))) unsigned int*)l, 16, 0, 0);
}

// ---------------------------------------------------------------------------
// LayerNorm: one block per token row. fp32 in -> bf16 out (w,b applied).
// ---------------------------------------------------------------------------
__global__ __launch_bounds__(256) void ln_kernel(
    const float* __restrict__ x, const float* __restrict__ w,
    const float* __restrict__ b, unsigned short* __restrict__ y)
{
    __shared__ float red[8];
    const int row = blockIdx.x;
    const int t = threadIdx.x;
    const float4 v = ((const float4*)(x + (size_t)row * DIM))[t];
    float s = v.x + v.y + v.z + v.w;
#pragma unroll
    for (int m = 1; m < 64; m <<= 1) s += __shfl_xor(s, m);
    if ((t & 63) == 0) red[t >> 6] = s;
    __syncthreads();
    const float mu = (red[0] + red[1] + red[2] + red[3]) * (1.0f / DIM);
    const float d0 = v.x - mu, d1 = v.y - mu, d2 = v.z - mu, d3 = v.w - mu;
    float q = d0 * d0 + d1 * d1 + d2 * d2 + d3 * d3;
#pragma unroll
    for (int m = 1; m < 64; m <<= 1) q += __shfl_xor(q, m);
    if ((t & 63) == 0) red[4 + (t >> 6)] = q;
    __syncthreads();
    const float var = (red[4] + red[5] + red[6] + red[7]) * (1.0f / DIM);
    const float rs = rsqrtf(var + 1e-5f);
    const float4 wv = ((const float4*)w)[t];
    const float4 bv = ((const float4*)b)[t];
    ushort4 o;
    o.x = f2bf(d0 * rs * wv.x + bv.x);
    o.y = f2bf(d1 * rs * wv.y + bv.y);
    o.z = f2bf(d2 * rs * wv.z + bv.z);
    o.w = f2bf(d3 * rs * wv.w + bv.w);
    ((ushort4*)(y + (size_t)row * DIM))[t] = o;
}

// ---------------------------------------------------------------------------
// Weight prepass: W [K][N] fp32 -> Wt [N][K] bf16 (64x64 tiles via LDS).
// ---------------------------------------------------------------------------
__global__ __launch_bounds__(256) void wtrans_kernel(
    const float* __restrict__ W, unsigned short* __restrict__ Wt, int K, int N)
{
    __shared__ float tile[64][65];
    const int n0 = blockIdx.x * 64, k0 = blockIdx.y * 64;
    const int t = threadIdx.x;
#pragma unroll
    for (int p = t; p < 1024; p += 256) {
        const int k = p >> 4, nq = (p & 15) * 4;
        const float4 v = *(const float4*)&W[(size_t)(k0 + k) * N + n0 + nq];
        tile[k][nq + 0] = v.x; tile[k][nq + 1] = v.y;
        tile[k][nq + 2] = v.z; tile[k][nq + 3] = v.w;
    }
    __syncthreads();
#pragma unroll
    for (int p = t; p < 1024; p += 256) {
        const int n = p >> 4, kq = (p & 15) * 4;
        ushort4 o;
        o.x = f2bf(tile[kq + 0][n]); o.y = f2bf(tile[kq + 1][n]);
        o.z = f2bf(tile[kq + 2][n]); o.w = f2bf(tile[kq + 3][n]);
        *(ushort4*)&Wt[(size_t)(n0 + n) * K + k0 + kq] = o;
    }
}

// ---------------------------------------------------------------------------
// Pipelined GEMM: C[M,N] = A[M,K](bf16) @ Bt[N,K](bf16)^T + bias.
// 128x128x32 tiles. Double-buffered LDS, ONE barrier per K-step:
//   barrier (waits vmcnt(0): prefetch batch from previous iter has landed)
//   issue async loads for k+1 into other buffer   <- stays in flight
//   compute on current buffer (16 MFMA + 8 ds_read hides load latency)
// MODE 0: out bf16 = acc+bias
// MODE 1: out bf16 = gelu(acc+bias)   (exact, erf)
// MODE 2: out fp32 += acc+bias        (residual accumulate, in-place)
// ---------------------------------------------------------------------------
template <int MODE>
__global__ __launch_bounds__(256) void gemm_pipe(
    const unsigned short* __restrict__ A, const unsigned short* __restrict__ Bt,
    const float* __restrict__ bias, void* __restrict__ Cout,
    int M, int K, int N)
{
    __shared__ __align__(16) unsigned short Al[2 * 128 * 32];
    __shared__ __align__(16) unsigned short Bl[2 * 128 * 32];

    const int bm = blockIdx.y * 128, bn = blockIdx.x * 128;
    const int tid = threadIdx.x;
    const int lane = tid & 63, wid = tid >> 6;
    const int lm = lane & 15, quad = lane >> 4;
    const int wm = (wid >> 1) * 64, wn = (wid & 1) * 64;

    floatx4 acc[4][4] = {};

    // staging: wave w owns rows [w*32, w*32+32) of each 128x32 tile.
    const unsigned short* gA = A + (size_t)(bm + wid * 32 + (lane >> 2)) * K + (lane & 3) * 8;
    const unsigned short* gB = Bt + (size_t)(bn + wid * 32 + (lane >> 2)) * K + (lane & 3) * 8;
    const int wof = wid * 1024;   // wave's row block within a buffer

    // prologue: stage k-tile 0 into buffer 0
    gld16(gA, &Al[wof]);
    gld16(gA + (size_t)16 * K, &Al[wof + 512]);
    gld16(gB, &Bl[wof]);
    gld16(gB + (size_t)16 * K, &Bl[wof + 512]);

    const int nk = K >> 5;
    for (int i = 0; i < nk; i++) {
        __syncthreads();   // vmcnt(0) waits batch i (had a full compute phase to land)
        const int cur = (i & 1) * 4096;
        if (i + 1 < nk) {
            const int nxt = ((i + 1) & 1) * 4096;
            const int kt = (i + 1) * 32;
            gld16(gA + kt, &Al[nxt + wof]);
            gld16(gA + (size_t)16 * K + kt, &Al[nxt + wof + 512]);
            gld16(gB + kt, &Bl[nxt + wof]);
            gld16(gB + (size_t)16 * K + kt, &Bl[nxt + wof + 512]);
        }
        short8 af[4], bf[4];
#pragma unroll
        for (int t = 0; t < 4; t++)
            af[t] = *(const short8*)&Al[cur + (wm + t * 16 + lm) * 32 + quad * 8];
#pragma unroll
        for (int t = 0; t < 4; t++)
            bf[t] = *(const short8*)&Bl[cur + (wn + t * 16 + lm) * 32 + quad * 8];
#pragma unroll
        for (int t = 0; t < 4; t++)
#pragma unroll
            for (int j = 0; j < 4; j++)
                acc[t][j] = __builtin_amdgcn_mfma_f32_16x16x32_bf16(
                    af[t], bf[j], acc[t][j], 0, 0, 0);
    }

    // epilogue (C/D layout: col = lane&15, row = quad*4 + reg)
#pragma unroll
    for (int i = 0; i < 4; i++) {
        const int row = bm + wm + i * 16 + quad * 4;
#pragma unroll
        for (int j = 0; j < 4; j++) {
            const int col = bn + wn + j * 16 + lm;
            const float bb = bias[col];
#pragma unroll
            for (int r = 0; r < 4; r++) {
                float v = acc[i][j][r] + bb;
                const size_t idx = (size_t)(row + r) * N + col;
                if constexpr (MODE == 0) {
                    ((unsigned short*)Cout)[idx] = f2bf(v);
                } else if constexpr (MODE == 1) {
                    const float g = 0.5f * v * (1.0f + erff(v * 0.70710678118654752f));
                    ((unsigned short*)Cout)[idx] = f2bf(g);
                } else {
                    ((float*)Cout)[idx] += v;
                }
            }
        }
    }
}

// ---------------------------------------------------------------------------
// V transpose: qkv[:, 2048 + h*64 + hd] -> Vt[b,h,hd,n]  (bf16)
// ---------------------------------------------------------------------------
__global__ __launch_bounds__(256) void vtrans_kernel(
    const unsigned short* __restrict__ qkv, unsigned short* __restrict__ Vt)
{
    __shared__ unsigned short tile[64][65];
    const int bh = blockIdx.x, nt = blockIdx.y;
    const int b = bh >> 4, h = bh & 15;
    const int t = threadIdx.x;
#pragma unroll
    for (int p = t; p < 4096; p += 256) {
        const int n = p >> 6, c = p & 63;
        tile[n][c] = qkv[(size_t)(b * SEQ + nt * 64 + n) * (3 * DIM) + 2 * DIM + h * HDIM + c];
    }
    __syncthreads();
#pragma unroll
    for (int p = t; p < 4096; p += 256) {
        const int hd = p >> 6, n = p & 63;
        Vt[((size_t)bh * HDIM + hd) * SEQ + nt * 64 + n] = tile[n][hd];
    }
}

// ---------------------------------------------------------------------------
// Fused flash attention. grid (64 bh, 16), 4 waves/block, one 16-row Q tile
// per wave, K-tiles of 32 keys. Out: O[b, n, h, hd] bf16.
// ---------------------------------------------------------------------------
__global__ __launch_bounds__(256) void attn_kernel(
    const unsigned short* __restrict__ qkv, const unsigned short* __restrict__ Vt,
    unsigned short* __restrict__ O)
{
    __shared__ __align__(16) unsigned short P[4][16 * 40];
    const int bh = blockIdx.x;
    const int b = bh >> 4, h = bh & 15;
    const int tid = threadIdx.x, lane = tid & 63, wid = tid >> 6;
    const int lm = lane & 15, quad = lane >> 4;
    const int q0 = (blockIdx.y * 4 + wid) * 16;

    const unsigned short* Qbase = qkv + (size_t)(b * SEQ) * (3 * DIM) + h * HDIM;
    const unsigned short* Kbase = Qbase + DIM;
    const unsigned short* Vbase = Vt + (size_t)bh * HDIM * SEQ;

    short8 aq[2];
#pragma unroll
    for (int t = 0; t < 2; t++)
        aq[t] = *(const short8*)&Qbase[(size_t)(q0 + lm) * (3 * DIM) + t * 32 + quad * 8];

    floatx4 o[4] = {};
    float mi[4], li[4];
#pragma unroll
    for (int r = 0; r < 4; r++) { mi[r] = -1e30f; li[r] = 0.0f; }
    unsigned short* Pw = P[wid];
    const float scale = 0.03125f;   // 1024^-0.5

    for (int kt = 0; kt < SEQ; kt += 32) {
        short8 bk[2][2];
#pragma unroll
        for (int s = 0; s < 2; s++)
#pragma unroll
            for (int t = 0; t < 2; t++)
                bk[s][t] = *(const short8*)&Kbase[(size_t)(kt + s * 16 + lm) * (3 * DIM) + t * 32 + quad * 8];
        floatx4 s0 = {}, s1 = {};
        s0 = __builtin_amdgcn_mfma_f32_16x16x32_bf16(aq[0], bk[0][0], s0, 0, 0, 0);
        s0 = __builtin_amdgcn_mfma_f32_16x16x32_bf16(aq[1], bk[0][1], s0, 0, 0, 0);
        s1 = __builtin_amdgcn_mfma_f32_16x16x32_bf16(aq[0], bk[1][0], s1, 0, 0, 0);
        s1 = __builtin_amdgcn_mfma_f32_16x16x32_bf16(aq[1], bk[1][1], s1, 0, 0, 0);

        float p0[4], p1[4];
#pragma unroll
        for (int r = 0; r < 4; r++) {
            const float x0 = s0[r] * scale, x1 = s1[r] * scale;
            float tmx = fmaxf(x0, x1);
#pragma unroll
            for (int m = 1; m < 16; m <<= 1) tmx = fmaxf(tmx, __shfl_xor(tmx, m));
            const float mn = fmaxf(mi[r], tmx);
            const float al = __expf(mi[r] - mn);
            p0[r] = __expf(x0 - mn);
            p1[r] = __expf(x1 - mn);
            float rsum = p0[r] + p1[r];
#pragma unroll
            for (int m = 1; m < 16; m <<= 1) rsum += __shfl_xor(rsum, m);
            li[r] = li[r] * al + rsum;
            mi[r] = mn;
#pragma unroll
            for (int ti = 0; ti < 4; ti++) o[ti][r] *= al;
        }
        // P: C-layout -> A-layout via LDS round trip
#pragma unroll
        for (int r = 0; r < 4; r++) {
            Pw[(quad * 4 + r) * 40 + lm]      = f2bf(p0[r]);
            Pw[(quad * 4 + r) * 40 + 16 + lm] = f2bf(p1[r]);
        }
        __syncthreads();
        const short8 pa = *(const short8*)&Pw[lm * 40 + quad * 8];
#pragma unroll
        for (int ti = 0; ti < 4; ti++) {
            const short8 bv = *(const short8*)&Vbase[(size_t)(ti * 16 + lm) * SEQ + kt + quad * 8];
            o[ti] = __builtin_amdgcn_mfma_f32_16x16x32_bf16(pa, bv, o[ti], 0, 0, 0);
        }
        __syncthreads();
    }
#pragma unroll
    for (int r = 0; r < 4; r++) {
        const float inv = 1.0f / li[r];
        const int qrow = q0 + quad * 4 + r;
        const size_t orow = (size_t)(b * SEQ + qrow) * DIM + h * HDIM;
#pragma unroll
        for (int ti = 0; ti < 4; ti++)
            O[orow + ti * 16 + lm] = f2bf(o[ti][r] * inv);
    }
}

// ---------------------------------------------------------------------------
extern "C" void kernel_launch(void* const* d_in, const int* in_sizes, int n_in,
                              void* d_out, int out_size, void* d_ws, size_t ws_size,
                              hipStream_t stream)
{
    (void)in_sizes; (void)n_in; (void)out_size; (void)ws_size;
    const float* x      = (const float*)d_in[0];
    const float* ln1_w  = (const float*)d_in[1];
    const float* ln1_b  = (const float*)d_in[2];
    const float* qkv_w  = (const float*)d_in[3];
    const float* qkv_b  = (const float*)d_in[4];
    const float* proj_w = (const float*)d_in[5];
    const float* proj_b = (const float*)d_in[6];
    const float* ln2_w  = (const float*)d_in[7];
    const float* ln2_b  = (const float*)d_in[8];
    const float* mlp_w1 = (const float*)d_in[9];
    const float* mlp_b1 = (const float*)d_in[10];
    const float* mlp_w2 = (const float*)d_in[11];
    const float* mlp_b2 = (const float*)d_in[12];

    char* p = (char*)d_ws;
    float* xbuf = (float*)p;                    p += (size_t)MTOK * DIM * 4;   // 16 MB
    unsigned short* y = (unsigned short*)p;     p += (size_t)MTOK * DIM * 2;   //  8 MB
    unsigned short* big = (unsigned short*)p;   p += (size_t)MTOK * MLPD * 2;  // 32 MB (qkv 24MB / H 32MB)
    unsigned short* Vt = (unsigned short*)p;    p += (size_t)MTOK * DIM * 2;   //  8 MB
    unsigned short* attno = (unsigned short*)p; p += (size_t)MTOK * DIM * 2;   //  8 MB
    // per-layer bf16 transposed weights (reused across layers)
    unsigned short* qkvT = (unsigned short*)p;  p += (size_t)DIM * 3 * DIM * 2;   // 6 MB
    unsigned short* projT = (unsigned short*)p; p += (size_t)DIM * DIM * 2;       // 2 MB
    unsigned short* mlp1T = (unsigned short*)p; p += (size_t)DIM * MLPD * 2;      // 8 MB
    unsigned short* mlp2T = (unsigned short*)p; p += (size_t)MLPD * DIM * 2;      // 8 MB

    hipMemcpyAsync(xbuf, x, (size_t)MTOK * DIM * 4, hipMemcpyDeviceToDevice, stream);

    for (int l = 0; l < DEPTH; l++) {
        // weight prepass: fp32 [K][N] -> bf16 [N][K], leaves weights L2/L3-hot
        wtrans_kernel<<<dim3(3 * DIM / 64, DIM / 64), 256, 0, stream>>>(
            qkv_w + (size_t)l * DIM * 3 * DIM, qkvT, DIM, 3 * DIM);
        wtrans_kernel<<<dim3(DIM / 64, DIM / 64), 256, 0, stream>>>(
            proj_w + (size_t)l * DIM * DIM, projT, DIM, DIM);
        wtrans_kernel<<<dim3(MLPD / 64, DIM / 64), 256, 0, stream>>>(
            mlp_w1 + (size_t)l * DIM * MLPD, mlp1T, DIM, MLPD);
        wtrans_kernel<<<dim3(DIM / 64, MLPD / 64), 256, 0, stream>>>(
            mlp_w2 + (size_t)l * MLPD * DIM, mlp2T, MLPD, DIM);

        ln_kernel<<<MTOK, 256, 0, stream>>>(xbuf, ln1_w + l * DIM, ln1_b + l * DIM, y);
        gemm_pipe<0><<<dim3(3 * DIM / 128, MTOK / 128), 256, 0, stream>>>(
            y, qkvT, qkv_b + (size_t)l * 3 * DIM, big, MTOK, DIM, 3 * DIM);
        vtrans_kernel<<<dim3(64, 16), 256, 0, stream>>>(big, Vt);
        attn_kernel<<<dim3(64, 16), 256, 0, stream>>>(big, Vt, attno);
        gemm_pipe<2><<<dim3(DIM / 128, MTOK / 128), 256, 0, stream>>>(
            attno, projT, proj_b + (size_t)l * DIM, xbuf, MTOK, DIM, DIM);
        ln_kernel<<<MTOK, 256, 0, stream>>>(xbuf, ln2_w + l * DIM, ln2_b + l * DIM, y);
        gemm_pipe<1><<<dim3(MLPD / 128, MTOK / 128), 256, 0, stream>>>(
            y, mlp1T, mlp_b1 + (size_t)l * MLPD, big, MTOK, DIM, MLPD);
        gemm_pipe<2><<<dim3(DIM / 128, MTOK / 128), 256, 0, stream>>>(
            big, mlp2T, mlp_b2 + (size_t)l * DIM, xbuf, MTOK, MLPD, DIM);
    }
    hipMemcpyAsync(d_out, xbuf, (size_t)MTOK * DIM * 4, hipMemcpyDeviceToDevice, stream);
}